// Round 1
// baseline (97.873 us; speedup 1.0000x reference)
//
#include <hip/hip_runtime.h>

#define T_LEN 512
#define LOG2E 1.4426950408889634f

// readlane: broadcast from a (uniform-indexed) lane into an SGPR value
__device__ __forceinline__ float rl(float v, int lane) {
    return __int_as_float(__builtin_amdgcn_readlane(__float_as_int(v), lane));
}

// quad_perm DPP: cross-lane within each 4-lane quad, single VALU instruction
template<int CTRL>
__device__ __forceinline__ float qperm(float v) {
    return __int_as_float(__builtin_amdgcn_mov_dpp(__float_as_int(v), CTRL, 0xF, 0xF, true));
}

// Layout: one 64-lane wave per batch element.
// lane l -> gate g = l&3 (0:i 1:f 2:g 3:o), hidden index k = l>>2.
// Weight row handled by lane l: row = g*16 + k  (PyTorch gate order i,f,g,o).
// The 4 gate activations of hidden index k live in one quad -> DPP gather.
// h broadcast each step via 16 v_readlane -> SGPRs feeding the next matvec.
__global__ __launch_bounds__(256, 2) void bilstm_head_kernel(
    const float* __restrict__ x,
    const float* __restrict__ W_ih_f, const float* __restrict__ W_hh_f,
    const float* __restrict__ b_ih_f, const float* __restrict__ b_hh_f,
    const float* __restrict__ W_ih_r, const float* __restrict__ W_hh_r,
    const float* __restrict__ b_ih_r, const float* __restrict__ b_hh_r,
    const float* __restrict__ W1, const float* __restrict__ b1,
    const float* __restrict__ W2, const float* __restrict__ b2,
    float* __restrict__ out)
{
    const int lane = threadIdx.x & 63;
    const int b    = blockIdx.x * 4 + (threadIdx.x >> 6);

    const int gate = lane & 3;
    const int k    = lane >> 2;
    const int row  = gate * 16 + k;

    // per-lane forward weights
    const float wih  = W_ih_f[row];
    const float bias = b_ih_f[row] + b_hh_f[row];
    float whh[16];
#pragma unroll
    for (int n = 0; n < 16; ++n) whh[n] = W_hh_f[row * 16 + n];

    // preload this batch's entire x row: 8 coalesced loads
    float xv[8];
#pragma unroll
    for (int i = 0; i < 8; ++i) xv[i] = x[b * T_LEN + i * 64 + lane];

    // per-lane activation constants: sigmoid for i/f/o, tanh (=2*sig(2x)-1) for g
    const bool  isg = (gate == 2);
    const float c1  = isg ? (-2.0f * LOG2E) : (-LOG2E);
    const float cm  = isg ? 2.0f : 1.0f;
    const float ca  = isg ? -1.0f : 0.0f;

    float hs[16];            // broadcast hidden state (uniform/SGPR values)
#pragma unroll
    for (int n = 0; n < 16; ++n) hs[n] = 0.0f;
    float c = 0.0f;          // cell state; only valid on lanes with gate==0

#pragma unroll
    for (int i = 0; i < 8; ++i) {
        const float xcur = xv[i];
#pragma unroll 4
        for (int tt = 0; tt < 64; ++tt) {
            const float xs = rl(xcur, tt);
            // z = x_t*W_ih[row] + bias + sum_k h_k * W_hh[row][k]
            float z0 = fmaf(xs, wih, bias);
            float z1 = 0.0f;
#pragma unroll
            for (int n = 0; n < 8; ++n) {
                z0 = fmaf(hs[2 * n],     whh[2 * n],     z0);
                z1 = fmaf(hs[2 * n + 1], whh[2 * n + 1], z1);
            }
            const float z = z0 + z1;
            // act = sigmoid(z) or tanh(z) depending on this lane's gate
            const float e   = __builtin_amdgcn_exp2f(z * c1);
            const float r   = __builtin_amdgcn_rcpf(1.0f + e);
            const float act = fmaf(r, cm, ca);
            // gather the quad's other gates (valid roles on gate==0 lanes)
            const float f_ = qperm<0xB1>(act);  // lane^1
            const float g_ = qperm<0x4E>(act);  // lane^2
            const float o_ = qperm<0x1B>(act);  // lane^3
            // c = sig(f)*c + sig(i)*tanh(g); h = sig(o)*tanh(c)
            c = fmaf(f_, c, act * g_);
            const float e2 = __builtin_amdgcn_exp2f(c * (-2.0f * LOG2E));
            const float th = fmaf(__builtin_amdgcn_rcpf(1.0f + e2), 2.0f, -1.0f);
            const float h  = o_ * th;
            // broadcast h_k (lives on lane 4k) to SGPRs for the next step
#pragma unroll
            for (int n = 0; n < 16; ++n) hs[n] = rl(h, 4 * n);
        }
    }
    // hs[] now holds the final forward hidden state h_fwd[0..15] (uniform).

    // ---- reverse direction: single LSTM step on x[:, T-1] from zero state ----
    const float wihr  = W_ih_r[row];
    const float biasr = b_ih_r[row] + b_hh_r[row];
    const float xlast = rl(xv[7], 63);

    const float zr   = fmaf(xlast, wihr, biasr);
    const float er   = __builtin_amdgcn_exp2f(zr * c1);
    const float rr_  = __builtin_amdgcn_rcpf(1.0f + er);
    const float actr = fmaf(rr_, cm, ca);
    const float gr   = qperm<0x4E>(actr);
    const float or_  = qperm<0x1B>(actr);
    const float cr   = actr * gr;                      // sig(i)*tanh(g), c0 = 0
    const float e2r  = __builtin_amdgcn_exp2f(cr * (-2.0f * LOG2E));
    const float thr_ = fmaf(__builtin_amdgcn_rcpf(1.0f + e2r), 2.0f, -1.0f);
    const float hbw  = or_ * thr_;

    float hr[16];
#pragma unroll
    for (int n = 0; n < 16; ++n) hr[n] = rl(hbw, 4 * n);

    // ---- MLP head: hid = LeakyReLU([h_fwd, h_bwd] @ W1.T + b1); out = hid @ W2.T + b2
    const int m = lane & 15;       // all 4 groups compute identical hid[m]
    float hid = b1[m];
#pragma unroll
    for (int n = 0; n < 16; ++n) hid = fmaf(hs[n], W1[m * 32 + n], hid);
#pragma unroll
    for (int n = 0; n < 16; ++n) hid = fmaf(hr[n], W1[m * 32 + 16 + n], hid);
    hid = (hid > 0.0f) ? hid : (0.2f * hid);

    float v = hid * W2[m];
    v += __shfl_xor(v, 1);
    v += __shfl_xor(v, 2);
    v += __shfl_xor(v, 4);
    v += __shfl_xor(v, 8);
    if (lane == 0) out[b] = v + b2[0];
}

extern "C" void kernel_launch(void* const* d_in, const int* in_sizes, int n_in,
                              void* d_out, int out_size, void* d_ws, size_t ws_size,
                              hipStream_t stream) {
    const float* x      = (const float*)d_in[0];
    const float* W_ih_f = (const float*)d_in[1];
    const float* W_hh_f = (const float*)d_in[2];
    const float* b_ih_f = (const float*)d_in[3];
    const float* b_hh_f = (const float*)d_in[4];
    const float* W_ih_r = (const float*)d_in[5];
    const float* W_hh_r = (const float*)d_in[6];
    const float* b_ih_r = (const float*)d_in[7];
    const float* b_hh_r = (const float*)d_in[8];
    const float* W1     = (const float*)d_in[9];
    const float* b1     = (const float*)d_in[10];
    const float* W2     = (const float*)d_in[11];
    const float* b2     = (const float*)d_in[12];
    float* out = (float*)d_out;

    const int B = in_sizes[0] / T_LEN;   // 2048
    dim3 grid(B / 4), block(256);
    hipLaunchKernelGGL(bilstm_head_kernel, grid, block, 0, stream,
                       x, W_ih_f, W_hh_f, b_ih_f, b_hh_f,
                       W_ih_r, W_hh_r, b_ih_r, b_hh_r,
                       W1, b1, W2, b2, out);
}

// Round 2
// 97.352 us; speedup vs baseline: 1.0053x; 1.0053x over previous
//
#include <hip/hip_runtime.h>

#define T_LEN 512
#define LOG2E 1.4426950408889634f

typedef float f32x2 __attribute__((ext_vector_type(2)));

// readlane: broadcast from a lane into a wave-uniform (SGPR) value
__device__ __forceinline__ float rl(float v, int lane) {
    return __int_as_float(__builtin_amdgcn_readlane(__float_as_int(v), lane));
}

// quad_perm DPP: cross-lane within each 4-lane quad, single VALU instruction
template<int CTRL>
__device__ __forceinline__ float qperm(float v) {
    return __int_as_float(__builtin_amdgcn_mov_dpp(__float_as_int(v), CTRL, 0xF, 0xF, true));
}

// Layout: one 64-lane wave per batch element.
// lane l -> gate g = l&3 (0:i 1:f 2:g 3:o), hidden index k = l>>2.
// Weight row handled by lane l: row = g*16 + k  (PyTorch gate order i,f,g,o).
// The 4 gate activations of hidden index k live in one quad -> DPP gather.
// h broadcast via 16 v_readlane into wave-uniform float2 pairs; the matvec
// runs as 8 v_pk_fma_f32 (packed dual fp32), h-pair as the scalar operand.
__global__ __launch_bounds__(256, 2) void bilstm_head_kernel(
    const float* __restrict__ x,
    const float* __restrict__ W_ih_f, const float* __restrict__ W_hh_f,
    const float* __restrict__ b_ih_f, const float* __restrict__ b_hh_f,
    const float* __restrict__ W_ih_r, const float* __restrict__ W_hh_r,
    const float* __restrict__ b_ih_r, const float* __restrict__ b_hh_r,
    const float* __restrict__ W1, const float* __restrict__ b1,
    const float* __restrict__ W2, const float* __restrict__ b2,
    float* __restrict__ out)
{
    const int lane = threadIdx.x & 63;
    const int b    = blockIdx.x * 4 + (threadIdx.x >> 6);

    const int gate = lane & 3;
    const int k    = lane >> 2;
    const int row  = gate * 16 + k;

    // per-lane forward weights, packed in pairs for v_pk_fma_f32
    const float wih  = W_ih_f[row];
    const float bias = b_ih_f[row] + b_hh_f[row];
    f32x2 whh2[8];
#pragma unroll
    for (int n = 0; n < 8; ++n)
        whh2[n] = *reinterpret_cast<const f32x2*>(&W_hh_f[row * 16 + 2 * n]);

    // preload this batch's entire x row: 8 coalesced loads
    float xv[8];
#pragma unroll
    for (int i = 0; i < 8; ++i) xv[i] = x[b * T_LEN + i * 64 + lane];

    // per-lane activation constants: sigmoid for i/f/o, tanh (=2*sig(2x)-1) for g
    const bool  isg = (gate == 2);
    const float c1  = isg ? (-2.0f * LOG2E) : (-LOG2E);
    const float cm  = isg ? 2.0f : 1.0f;
    const float ca  = isg ? -1.0f : 0.0f;

    f32x2 h2[8];             // broadcast hidden state pairs (wave-uniform)
#pragma unroll
    for (int n = 0; n < 8; ++n) h2[n] = (f32x2){0.0f, 0.0f};
    float c = 0.0f;          // cell state; role-valid on gate==0 lanes

#pragma unroll
    for (int i = 0; i < 8; ++i) {
        const float xcur = xv[i];
#pragma unroll 8
        for (int tt = 0; tt < 64; ++tt) {
            const float xs = rl(xcur, tt);
            const float xz = fmaf(xs, wih, bias);
            // z = xz + sum_k h_k * W_hh[row][k]  -- packed dual-fp32 matvec
            f32x2 z2 = (f32x2){xz, 0.0f};
#pragma unroll
            for (int n = 0; n < 8; ++n)
                z2 = __builtin_elementwise_fma(whh2[n], h2[n], z2);
            const float z = z2.x + z2.y;
            // act = sigmoid(z) or tanh(z) depending on this lane's gate
            const float e   = __builtin_amdgcn_exp2f(z * c1);
            const float r   = __builtin_amdgcn_rcpf(1.0f + e);
            const float act = fmaf(r, cm, ca);
            // gather the quad's other gates
            const float f_ = qperm<0xB1>(act);  // lane^1
            const float g_ = qperm<0x4E>(act);  // lane^2
            const float o_ = qperm<0x1B>(act);  // lane^3
            // c = sig(f)*c + sig(i)*tanh(g); h = sig(o)*tanh(c)
            c = fmaf(f_, c, act * g_);
            const float e2 = __builtin_amdgcn_exp2f(c * (-2.0f * LOG2E));
            const float th = fmaf(__builtin_amdgcn_rcpf(1.0f + e2), 2.0f, -1.0f);
            const float h  = o_ * th;
            // broadcast h_k (lives on lane 4k) into uniform pairs
#pragma unroll
            for (int n = 0; n < 8; ++n)
                h2[n] = (f32x2){ rl(h, 8 * n), rl(h, 8 * n + 4) };
        }
    }
    // h2[] now holds the final forward hidden state h_fwd[0..15] (uniform).
    float hs[16];
#pragma unroll
    for (int n = 0; n < 8; ++n) { hs[2 * n] = h2[n].x; hs[2 * n + 1] = h2[n].y; }

    // ---- reverse direction: single LSTM step on x[:, T-1] from zero state ----
    const float wihr  = W_ih_r[row];
    const float biasr = b_ih_r[row] + b_hh_r[row];
    const float xlast = rl(xv[7], 63);

    const float zr   = fmaf(xlast, wihr, biasr);
    const float er   = __builtin_amdgcn_exp2f(zr * c1);
    const float rr_  = __builtin_amdgcn_rcpf(1.0f + er);
    const float actr = fmaf(rr_, cm, ca);
    const float gr   = qperm<0x4E>(actr);
    const float or_  = qperm<0x1B>(actr);
    const float cr   = actr * gr;                      // sig(i)*tanh(g), c0 = 0
    const float e2r  = __builtin_amdgcn_exp2f(cr * (-2.0f * LOG2E));
    const float thr_ = fmaf(__builtin_amdgcn_rcpf(1.0f + e2r), 2.0f, -1.0f);
    const float hbw  = or_ * thr_;

    float hr[16];
#pragma unroll
    for (int n = 0; n < 16; ++n) hr[n] = rl(hbw, 4 * n);

    // ---- MLP head: hid = LeakyReLU([h_fwd, h_bwd] @ W1.T + b1); out = hid @ W2.T + b2
    const int m = lane & 15;       // all 4 groups compute identical hid[m]
    float hid = b1[m];
#pragma unroll
    for (int n = 0; n < 16; ++n) hid = fmaf(hs[n], W1[m * 32 + n], hid);
#pragma unroll
    for (int n = 0; n < 16; ++n) hid = fmaf(hr[n], W1[m * 32 + 16 + n], hid);
    hid = (hid > 0.0f) ? hid : (0.2f * hid);

    float v = hid * W2[m];
    v += __shfl_xor(v, 1);
    v += __shfl_xor(v, 2);
    v += __shfl_xor(v, 4);
    v += __shfl_xor(v, 8);
    if (lane == 0) out[b] = v + b2[0];
}

extern "C" void kernel_launch(void* const* d_in, const int* in_sizes, int n_in,
                              void* d_out, int out_size, void* d_ws, size_t ws_size,
                              hipStream_t stream) {
    const float* x      = (const float*)d_in[0];
    const float* W_ih_f = (const float*)d_in[1];
    const float* W_hh_f = (const float*)d_in[2];
    const float* b_ih_f = (const float*)d_in[3];
    const float* b_hh_f = (const float*)d_in[4];
    const float* W_ih_r = (const float*)d_in[5];
    const float* W_hh_r = (const float*)d_in[6];
    const float* b_ih_r = (const float*)d_in[7];
    const float* b_hh_r = (const float*)d_in[8];
    const float* W1     = (const float*)d_in[9];
    const float* b1     = (const float*)d_in[10];
    const float* W2     = (const float*)d_in[11];
    const float* b2     = (const float*)d_in[12];
    float* out = (float*)d_out;

    const int B = in_sizes[0] / T_LEN;   // 2048
    dim3 grid(B / 4), block(256);
    hipLaunchKernelGGL(bilstm_head_kernel, grid, block, 0, stream,
                       x, W_ih_f, W_hh_f, b_ih_f, b_hh_f,
                       W_ih_r, W_hh_r, b_ih_r, b_hh_r,
                       W1, b1, W2, b2, out);
}